// Round 1
// baseline (628.786 us; speedup 1.0000x reference)
//
#include <hip/hip_runtime.h>
#include <math.h>

#define H 4096
#define E 8

// Kernel A: router logits + argmax. One block, 8 waves; wave e computes logit e.
__global__ __launch_bounds__(512) void router_kernel(
    const float* __restrict__ x,
    const float* __restrict__ router_w,
    const float* __restrict__ router_b,
    int* __restrict__ idx_out)
{
    const int tid  = threadIdx.x;
    const int wave = tid >> 6;   // expert index 0..7
    const int lane = tid & 63;

    const float4* rw = (const float4*)(router_w + wave * H);
    const float4* x4 = (const float4*)x;

    float acc = 0.f;
#pragma unroll
    for (int k = 0; k < 16; ++k) {          // 16 * 64 lanes * 4 floats = 4096
        const int i = k * 64 + lane;
        float4 a = rw[i];
        float4 b = x4[i];
        acc += a.x * b.x + a.y * b.y + a.z * b.z + a.w * b.w;
    }
#pragma unroll
    for (int off = 32; off > 0; off >>= 1)
        acc += __shfl_down(acc, off, 64);

    __shared__ float logits[E];
    if (lane == 0) logits[wave] = acc + router_b[wave];
    __syncthreads();

    if (tid == 0) {
        int best = 0;
        float bv = logits[0];
#pragma unroll
        for (int e = 1; e < E; ++e) {
            if (logits[e] > bv) { bv = logits[e]; best = e; }  // first-max wins, matches argmax
        }
        *idx_out = best;
    }
}

// Kernel B: per output row j: dot(x, expert_w[idx][j,:]) and dot(x, gate_w[j,:]),
// then out[j] = sigmoid(.)*tanh(.) + (1-sigmoid(.))*x[j].
// One wave per row; 4 waves (rows) per block; x staged in LDS once per block.
__global__ __launch_bounds__(256) void moe_gemv_kernel(
    const float* __restrict__ x,
    const float* __restrict__ expert_w,
    const float* __restrict__ expert_b,
    const float* __restrict__ gate_w,
    const float* __restrict__ gate_b,
    const int* __restrict__ idx_ptr,
    float* __restrict__ out)
{
    __shared__ float4 xs[H / 4];   // 16 KB

    const int tid = threadIdx.x;

    // Stage x into LDS (1024 float4 over 256 threads).
    const float4* x4 = (const float4*)x;
#pragma unroll
    for (int k = 0; k < 4; ++k)
        xs[k * 256 + tid] = x4[k * 256 + tid];

    const int idx = *idx_ptr;      // scalar, L2-hit broadcast
    __syncthreads();

    const int wave = tid >> 6;
    const int lane = tid & 63;
    const int j = blockIdx.x * 4 + wave;   // output row for this wave

    const float4* er = (const float4*)(expert_w + ((size_t)idx * H + (size_t)j) * H);
    const float4* gr = (const float4*)(gate_w + (size_t)j * H);

    float acc_e = 0.f, acc_g = 0.f;
#pragma unroll
    for (int k = 0; k < 16; ++k) {
        const int i = k * 64 + lane;       // coalesced: wave covers 1 KB per load
        float4 a  = er[i];
        float4 b  = gr[i];
        float4 xv = xs[i];
        acc_e += a.x * xv.x + a.y * xv.y + a.z * xv.z + a.w * xv.w;
        acc_g += b.x * xv.x + b.y * xv.y + b.z * xv.z + b.w * xv.w;
    }

#pragma unroll
    for (int off = 32; off > 0; off >>= 1) {
        acc_e += __shfl_down(acc_e, off, 64);
        acc_g += __shfl_down(acc_g, off, 64);
    }

    if (lane == 0) {
        const float mix = tanhf(acc_e + expert_b[(size_t)idx * H + j]);
        const float gpre = acc_g + gate_b[j];
        const float g = 1.f / (1.f + expf(-gpre));
        const float xj = ((const float*)xs)[j];
        out[j] = g * mix + (1.f - g) * xj;
    }
}

extern "C" void kernel_launch(void* const* d_in, const int* in_sizes, int n_in,
                              void* d_out, int out_size, void* d_ws, size_t ws_size,
                              hipStream_t stream) {
    const float* x        = (const float*)d_in[0];
    const float* expert_w = (const float*)d_in[1];
    const float* expert_b = (const float*)d_in[2];
    const float* router_w = (const float*)d_in[3];
    const float* router_b = (const float*)d_in[4];
    const float* gate_w   = (const float*)d_in[5];
    const float* gate_b   = (const float*)d_in[6];
    float* out = (float*)d_out;
    int* idx   = (int*)d_ws;

    router_kernel<<<1, 512, 0, stream>>>(x, router_w, router_b, idx);
    moe_gemv_kernel<<<H / 4, 256, 0, stream>>>(x, expert_w, expert_b, gate_w, gate_b, idx, out);
}

// Round 2
// 623.883 us; speedup vs baseline: 1.0079x; 1.0079x over previous
//
#include <hip/hip_runtime.h>
#include <math.h>

#define H 4096
#define E 8

// Fully fused: router (redundantly per block, deterministic) + dual GEMV + gate combine.
// 512 blocks x 512 threads; wave w in block b owns output row j = b*8 + w.
__global__ __launch_bounds__(512) void fused_moe_gate_kernel(
    const float* __restrict__ x,
    const float* __restrict__ expert_w,
    const float* __restrict__ expert_b,
    const float* __restrict__ router_w,
    const float* __restrict__ router_b,
    const float* __restrict__ gate_w,
    const float* __restrict__ gate_b,
    float* __restrict__ out)
{
    __shared__ float4 xs[H / 4];   // 16 KB staged x
    __shared__ float logits[E];
    __shared__ int s_idx;

    const int tid  = threadIdx.x;
    const int wave = tid >> 6;     // 0..7
    const int lane = tid & 63;

    // ---- Stage x into LDS (1024 float4 over 512 threads) ----
    const float4* x4 = (const float4*)x;
#pragma unroll
    for (int k = 0; k < 2; ++k)
        xs[k * 512 + tid] = x4[k * 512 + tid];
    __syncthreads();

    // ---- Router: wave e computes logit e (reads L2-resident 16 KB row) ----
    {
        const float4* rw = (const float4*)(router_w + wave * H);
        float acc = 0.f;
#pragma unroll
        for (int k = 0; k < 16; ++k) {
            const int i = k * 64 + lane;
            float4 a  = rw[i];
            float4 xv = xs[i];
            acc += a.x * xv.x + a.y * xv.y + a.z * xv.z + a.w * xv.w;
        }
#pragma unroll
        for (int off = 32; off > 0; off >>= 1)
            acc += __shfl_down(acc, off, 64);
        if (lane == 0) logits[wave] = acc + router_b[wave];
    }
    __syncthreads();

    // First-max-wins argmax (matches jnp.argmax); done by thread 0 while other
    // waves proceed to the gate dot below only after the barrier — so instead
    // we let ALL threads fall through to the gate dot and publish idx after.
    if (tid == 0) {
        int best = 0;
        float bv = logits[0];
#pragma unroll
        for (int e = 1; e < E; ++e)
            if (logits[e] > bv) { bv = logits[e]; best = e; }
        s_idx = best;
    }

    const int j = blockIdx.x * 8 + wave;   // this wave's output row

    // ---- Gate dot (idx-independent): hides argmax/barrier latency ----
    const float4* gr = (const float4*)(gate_w + (size_t)j * H);
    float acc_g = 0.f;
#pragma unroll
    for (int k = 0; k < 16; ++k) {
        const int i = k * 64 + lane;
        float4 b  = gr[i];
        float4 xv = xs[i];
        acc_g += b.x * xv.x + b.y * xv.y + b.z * xv.z + b.w * xv.w;
    }

    __syncthreads();                       // publishes s_idx
    const int idx = s_idx;

    // ---- Expert dot ----
    const float4* er = (const float4*)(expert_w + ((size_t)idx * H + (size_t)j) * H);
    float acc_e = 0.f;
#pragma unroll
    for (int k = 0; k < 16; ++k) {
        const int i = k * 64 + lane;
        float4 a  = er[i];
        float4 xv = xs[i];
        acc_e += a.x * xv.x + a.y * xv.y + a.z * xv.z + a.w * xv.w;
    }

    // ---- Wave reductions (both dots) ----
#pragma unroll
    for (int off = 32; off > 0; off >>= 1) {
        acc_e += __shfl_down(acc_e, off, 64);
        acc_g += __shfl_down(acc_g, off, 64);
    }

    if (lane == 0) {
        const float mix  = tanhf(acc_e + expert_b[(size_t)idx * H + j]);
        const float gpre = acc_g + gate_b[j];
        const float g    = 1.f / (1.f + expf(-gpre));
        const float xj   = ((const float*)xs)[j];
        out[j] = g * mix + (1.f - g) * xj;
    }
}

extern "C" void kernel_launch(void* const* d_in, const int* in_sizes, int n_in,
                              void* d_out, int out_size, void* d_ws, size_t ws_size,
                              hipStream_t stream) {
    const float* x        = (const float*)d_in[0];
    const float* expert_w = (const float*)d_in[1];
    const float* expert_b = (const float*)d_in[2];
    const float* router_w = (const float*)d_in[3];
    const float* router_b = (const float*)d_in[4];
    const float* gate_w   = (const float*)d_in[5];
    const float* gate_b   = (const float*)d_in[6];
    float* out = (float*)d_out;

    fused_moe_gate_kernel<<<H / 8, 512, 0, stream>>>(
        x, expert_w, expert_b, router_w, router_b, gate_w, gate_b, out);
}